// Round 3
// baseline (81.896 us; speedup 1.0000x reference)
//
#include <hip/hip_runtime.h>

// GraphAdjacencyLayer: W[i][j] = thresh((fn_i . fn_j)^2), fn = row-normalized features.
// N x 128 fp32 in, N x N fp32 out (N=8192). Output 256 MB is the write roofline (~39 us).
//
// K1: fn = f32_normalize(row); store bf16 fn to d_ws (2 MB, L2-resident).
// K2: Gram via bf16 MFMA with SWAPPED operands: mfma(b, a) makes each lane's f32x4
//     acc hold 4 CONSECUTIVE output columns of one row -> threshold in-register and
//     store float4 (1 KB per wave store-inst). Stores are streamed per m-slice so the
//     write stream stays continuous instead of one terminal burst.

typedef __bf16 bf16x8 __attribute__((ext_vector_type(8)));
typedef float f32x4 __attribute__((ext_vector_type(4)));

// ---------------- K1: row-normalize fp32 -> bf16 ----------------------------
__global__ __launch_bounds__(256)
void norm_cvt_kernel(const float* __restrict__ F, unsigned short* __restrict__ Fb, int N)
{
    const int gtid = blockIdx.x * 256 + threadIdx.x;
    const int row  = gtid >> 5;
    const int c    = gtid & 31;          // float4 column
    if (row >= N) return;

    float4 v = ((const float4*)F)[(size_t)row * 32 + c];
    float ss = v.x * v.x + v.y * v.y + v.z * v.z + v.w * v.w;
    #pragma unroll
    for (int m = 1; m <= 16; m <<= 1) ss += __shfl_xor(ss, m, 64);   // within 32-group
    const float s = 1.0f / (sqrtf(ss) + 1e-12f);

    ushort4 u;
    u.x = __builtin_bit_cast(unsigned short, (__bf16)(v.x * s));
    u.y = __builtin_bit_cast(unsigned short, (__bf16)(v.y * s));
    u.z = __builtin_bit_cast(unsigned short, (__bf16)(v.z * s));
    u.w = __builtin_bit_cast(unsigned short, (__bf16)(v.w * s));
    ((ushort4*)Fb)[(size_t)row * 32 + c] = u;
}

// ---------------- K2: Gram + threshold, float4 stores ------------------------
// 128x128 tile per 256-thread block (4 waves, 2x2 of 64x64). K=128, no K-loop.
// acc[n] = mfma(b[n], a)  =>  D[p][q]: q=lane&15 -> output ROW, p=(lane>>4)*4+reg
// -> output COLS (4 consecutive). Lane stores one float4 of W per fragment.
__global__ __launch_bounds__(256, 3)
void gram_thresh_kernel(const unsigned short* __restrict__ Fb, float* __restrict__ out, int N)
{
    const int tid  = threadIdx.x;
    const int lane = tid & 63;
    const int wid  = tid >> 6;
    const int wm   = wid >> 1;
    const int wn   = wid & 1;
    const int fr   = lane & 15;          // fragment row index
    const int fkq  = lane >> 4;          // k-quad / col-quad 0..3

    const int rowTile = blockIdx.y * 128;
    const int colTile = blockIdx.x * 128;

    const bf16x8* __restrict__ base = (const bf16x8*)Fb;   // row stride = 16 chunks
    const int rowA0 = rowTile + wm * 64 + fr;
    const int rowB0 = colTile + wn * 64 + fr;

    // preload all B fragments (output-column rows): 16 loads, 64 VGPR
    bf16x8 b[4][4];
    #pragma unroll
    for (int n = 0; n < 4; ++n)
        #pragma unroll
        for (int ks = 0; ks < 4; ++ks)
            b[n][ks] = base[(size_t)(rowB0 + n * 16) * 16 + ks * 4 + fkq];

    const float c1 = 0.9486832980505138f;  // sqrt(0.9)
    const float c2 = 0.7071067811865476f;  // sqrt(0.5)
    const bool diagBlock = (rowTile == colTile);

    #pragma unroll
    for (int m = 0; m < 4; ++m) {
        bf16x8 a[4];
        #pragma unroll
        for (int ks = 0; ks < 4; ++ks)
            a[ks] = base[(size_t)(rowA0 + m * 16) * 16 + ks * 4 + fkq];

        f32x4 acc[4];
        #pragma unroll
        for (int n = 0; n < 4; ++n) acc[n] = (f32x4){0.f, 0.f, 0.f, 0.f};

        #pragma unroll
        for (int ks = 0; ks < 4; ++ks)
            #pragma unroll
            for (int n = 0; n < 4; ++n)
                acc[n] = __builtin_amdgcn_mfma_f32_16x16x32_bf16(b[n][ks], a[ks], acc[n], 0, 0, 0);

        const int grow = rowTile + wm * 64 + m * 16 + fr;
        float* __restrict__ orow = out + (size_t)grow * N;

        #pragma unroll
        for (int n = 0; n < 4; ++n) {
            const int c0 = colTile + wn * 64 + n * 16 + fkq * 4;
            float4 w;
            {
                const float g0 = fabsf(acc[n][0]);
                const float g1 = fabsf(acc[n][1]);
                const float g2 = fabsf(acc[n][2]);
                const float g3 = fabsf(acc[n][3]);
                w.x = g0 >= c1 ? 1.0f : (g0 >= c2 ? 0.5f : 0.0f);
                w.y = g1 >= c1 ? 1.0f : (g1 >= c2 ? 0.5f : 0.0f);
                w.z = g2 >= c1 ? 1.0f : (g2 >= c2 ? 0.5f : 0.0f);
                w.w = g3 >= c1 ? 1.0f : (g3 >= c2 ? 0.5f : 0.0f);
            }
            if (diagBlock) {
                const int d = grow - c0;        // component hit if 0..3
                if (d == 0) w.x = 0.0f;
                else if (d == 1) w.y = 0.0f;
                else if (d == 2) w.z = 0.0f;
                else if (d == 3) w.w = 0.0f;
            }
            *(float4*)(orow + c0) = w;
        }
    }
}

extern "C" void kernel_launch(void* const* d_in, const int* in_sizes, int n_in,
                              void* d_out, int out_size, void* d_ws, size_t ws_size,
                              hipStream_t stream) {
    const float* features = (const float*)d_in[0];
    float* out = (float*)d_out;
    const int D = 128;
    const int N = in_sizes[0] / D;   // 8192

    unsigned short* Fb = (unsigned short*)d_ws;
    const int k1_blocks = (N * 32 + 255) / 256;
    norm_cvt_kernel<<<k1_blocks, 256, 0, stream>>>(features, Fb, N);
    dim3 grid(N / 128, N / 128);
    gram_thresh_kernel<<<grid, dim3(256), 0, stream>>>(Fb, out, N);
}